// Round 21
// baseline (122.818 us; speedup 1.0000x reference)
//
#include <hip/hip_runtime.h>

#define CELLS 81
#define ND 9
#define HID 100
#define NP 52    // padded unit-pairs: 50 real + 2 zero
#define PPW 13   // pairs per wave (4 waves x 13 = 52)
#define NREG 8   // W2 pairs persisted in VGPRs per wave (rest via LDS)

typedef float v2f __attribute__((ext_vector_type(2)));

#define W1P_SZ (9 * NP * 8)           // 3744 floats
#define W2P_OFF W1P_SZ                // 3744
#define W2P_SZ (NP * 20)              // 1040 floats
#define NE_OFF (W2P_OFF + W2P_SZ)     // 4784: ne_arr[1024] (int)
#define ORD_OFF (NE_OFF + 1024)       // 5808: order[2*1024] (int)

// Snake (boustrophedon) slot map: blocks b and b+256 land on the SAME CU
// (b%8 = XCD, (b/8)%32 = CU-in-XCD). Descending-sorted slots striped
// ascending stack long+medium+medium on one CU (rank 0's CU got ranks
// {0,256,512} = ~87 block-iters -> the 105us critical path). Reversing
// every stripe past the first pairs longest with shortest: ~58 iters max.
__device__ __forceinline__ int physSlot(int p) {
    return (p < 256) ? p : ((p & ~255) | (255 - (p & 255)));
}

// Prolog 1: pack weight tables (first ~75 blocks' worth of gids) and write
// each board's empty-count to ne_arr[b]. NO atomics, NO memset dependency.
__global__ __launch_bounds__(64) void prep_kernel(
    const float* __restrict__ x_all,
    const float* __restrict__ W1, const float* __restrict__ W2,
    float* __restrict__ ws, int* __restrict__ ne_arr, int nBoards)
{
    const int b = blockIdx.x, t = threadIdx.x;
    const int gid = b * 64 + t;

    if (gid < W1P_SZ) {
        int i = gid >> 3, k = gid & 7;
        int d = i / NP, j = i - d * NP;
        float v = 0.f;
        if (j < 50 && k < 6) {
            int u = 2 * j + (k & 1);
            v = W1[u*27 + (k >> 1) * 9 + d];
        }
        ws[gid] = v;
    } else if (gid < NE_OFF) {
        int f = gid - W2P_OFF;
        int j = f / 20, k = f - j * 20;
        float v = 0.f;
        if (j < 50 && k < 18) {
            int d = k >> 1, u = 2 * j + (k & 1);
            v = W2[d*HID + u];
        }
        ws[gid] = v;
    }

    if (b >= nBoards) return;

    const float* xb = x_all + (size_t)b * (CELLS * ND);
    float mx = 0.f;
    #pragma unroll
    for (int d = 0; d < ND; ++d) mx = fmaxf(mx, xb[t*ND + d]);
    bool e1 = (mx < 0.5f);
    bool e2 = false;
    if (t < CELLS - 64) {
        float m2 = 0.f;
        #pragma unroll
        for (int d = 0; d < ND; ++d) m2 = fmaxf(m2, xb[(64+t)*ND + d]);
        e2 = (m2 < 0.5f);
    }
    unsigned long long m1 = __ballot(e1), m2b = __ballot(e2);
    if (t == 0) {
        int ne = __popcll(m1) + __popcll(m2b);
        if (ne > 64) ne = 64;
        ne_arr[b] = ne;
    }
}

// Prolog 2: deterministic atomic-free counting sort; all block slots go
// through physSlot. Block 65 writes the -1 tail/odd hole (phys-mapped) so
// every order[] slot is written each replay (no memset needed).
__global__ __launch_bounds__(256) void scatter_kernel(
    const int* __restrict__ ne_arr, int* __restrict__ order, int nBoards)
{
    __shared__ int sh_ne[1024];
    __shared__ int cntS[65];
    __shared__ int baseS, nBigS, nUsedS, oddS;
    const int t = threadIdx.x;
    const int bk = blockIdx.x;

    for (int i = t; i < 1024; i += 256)
        sh_ne[i] = (i < nBoards) ? ne_arr[i] : -1;
    __syncthreads();
    if (t < 65) {
        int c = 0;
        for (int j = 0; j < 1024; ++j) c += (sh_ne[j] == t) ? 1 : 0;
        cntS[t] = c;
    }
    __syncthreads();

    if (bk < 65) {
        if (t == 0) {
            int acc = 0, nb = 0;
            for (int k = 64; k > bk; --k) acc += cntS[k];
            for (int k = 64; k > 32; --k) nb += cntS[k];
            baseS = acc; nBigS = nb;
        }
        __syncthreads();
        const int base = baseS, nBig = nBigS;
        if (t < 64) {                       // wave 0: ballot-compact members
            int r = 0;
            for (int chunk = 0; chunk < 16; ++chunk) {
                int i = chunk * 64 + t;
                bool m = (sh_ne[i] == bk);
                unsigned long long mk = __ballot(m);
                if (m) {
                    int rk = r + __popcll(mk & ((1ull << t) - 1ull));
                    int pos = base + rk;
                    if (bk > 32) {          // joined big: own block
                        int pb = physSlot(pos);
                        order[2*pb] = i; order[2*pb + 1] = i;
                    } else {
                        int rr = pos - nBig;
                        int blk = physSlot(nBig + (rr >> 1));
                        order[2*blk + (rr & 1)] = i;
                    }
                }
                r += __popcll(mk);
            }
        }
    } else {
        if (t == 0) {
            int nb = 0, ns = 0;
            for (int k = 64; k > 32; --k) nb += cntS[k];
            for (int k = 0; k <= 32; ++k) ns += cntS[k];
            nBigS = nb;
            nUsedS = nb + (ns + 1) / 2;
            oddS = ns & 1;
        }
        __syncthreads();
        const int nUsed = nUsedS;
        for (int i = nUsed + t; i < 1024; i += 256) {
            int pb = physSlot(i);
            order[2*pb] = -1; order[2*pb + 1] = -1;
        }
        if (t == 0 && oddS && nUsed > 0)
            order[2*physSlot(nUsed - 1) + 1] = -1;  // lone small -> joined
    }
}

// R13-proven solver (byte-identical): 40.4 KB LDS -> 4 blocks/CU. W2 for
// NREG pairs in registers, loaded from LDS (R15 lesson: global-loaded
// uniforms get rematerialized as in-loop global loads at ~200cy each).
__global__ __launch_bounds__(256, 2) void sudoku_kernel(
    const float* __restrict__ x_all,
    const float* __restrict__ ws,
    const int* __restrict__ order,
    float* __restrict__ out, int nBoards)
{
    const int tid = threadIdx.x;      // 4 waves x 13 pairs
    const int wv  = tid >> 6;
    const int lw  = tid & 63;
    const int h   = lw >> 5;          // 32-lane segment within wave
    const int jbase = wv * PPW;

    const int s0  = order[2 * blockIdx.x];
    const int s1r = order[2 * blockIdx.x + 1];
    if (s0 < 0) return;
    const int s1 = (s1r < 0) ? s0 : s1r;
    const bool joined = (s0 == s1);   // one 64-lane board (big or lone small)
    const int myBoard = h ? s1 : s0;
    const int idx = joined ? 0 : h;   // cnt/digit slot

    float* pom = out + (size_t)myBoard * (CELLS * ND);

    __shared__ __align__(16) float w1s[W1P_SZ];      // 14976 B
    __shared__ __align__(16) float w2s[W2P_SZ];      // 4160 B
    __shared__ float parts[2][4][ND][64];            // 18432 B, conflict-free
    __shared__ float cnt[2][3 * 81];                 // 1944 B
    __shared__ int   digit[2][CELLS];                // 648 B

    for (int i = tid; i < W1P_SZ / 4; i += 256)
        ((float4*)w1s)[i] = ((const float4*)ws)[i];
    for (int i = tid; i < W2P_SZ / 4; i += 256)
        ((float4*)w2s)[i] = ((const float4*)(ws + W2P_OFF))[i];
    for (int i = tid; i < 2 * 243; i += 256) (&cnt[0][0])[i] = 0.f;
    __syncthreads();

    float w2reg[NREG][18];
    #pragma unroll
    for (int j = 0; j < NREG; ++j) {
        const float* qq = &w2s[(jbase + j) * 20];
        #pragma unroll
        for (int k = 0; k < 18; ++k) w2reg[j][k] = qq[k];
    }

    {
        const int slot = (tid < 128) ? 0 : 1;
        const int t = (tid < 128) ? tid : tid - 128;
        const bool doSlot = (slot == 0) || !joined;
        const int bd = slot ? s1 : s0;
        const float* xb = x_all + (size_t)bd * (CELLS * ND);
        float* pob = out + (size_t)bd * (CELLS * ND);
        if (doSlot) {
            if (t < CELLS) {
                int dig = -1;
                #pragma unroll
                for (int d = 0; d < ND; ++d)
                    if (dig < 0 && xb[t*ND + d] > 0.5f) dig = d;
                digit[slot][t] = dig;
                if (dig >= 0) {
                    int r = t/9, c = t%9, b = (r/3)*3 + c/3;
                    atomicAdd(&cnt[slot][r*9 + dig], 1.f);
                    atomicAdd(&cnt[slot][81 + c*9 + dig], 1.f);
                    atomicAdd(&cnt[slot][162 + b*9 + dig], 1.f);
                }
            }
            for (int i = t; i < CELLS * ND; i += 128) pob[i] = xb[i];
        }
    }
    __syncthreads();

    const int rank = joined ? lw : (lw & 31);
    int myq = 127;
    int ne0 = 0, ne1 = 0;
    for (int q = 0; q < CELLS; ++q)
        if (digit[0][q] < 0) { if (idx == 0 && ne0 == rank) myq = q; ++ne0; }
    if (!joined) {
        for (int q = 0; q < CELLS; ++q)
            if (digit[1][q] < 0) { if (idx == 1 && ne1 == rank) myq = q; ++ne1; }
    } else ne1 = ne0;
    if (ne0 > 64) ne0 = 64;
    if (ne1 > 64) ne1 = 64;
    const int ne_mine = idx ? ne1 : ne0;
    const int itMax = max(ne0, ne1);
    bool active = (rank < ne_mine);

    const int myr = (myq < 81) ? myq / 9 : 0;
    const int myc = (myq < 81) ? myq % 9 : 0;
    const int myb = (myr / 3) * 3 + myc / 3;

    float crr[9], ccc[9], cbb[9];
    #pragma unroll
    for (int j = 0; j < 9; ++j) {
        crr[j] = cnt[idx][myr*9 + j];
        ccc[j] = cnt[idx][81 + myc*9 + j];
        cbb[j] = cnt[idx][162 + myb*9 + j];
    }
    v2f z2[PPW];
    #pragma unroll
    for (int j = 0; j < PPW; ++j) {
        v2f a = (v2f){0.f, 0.f};
        #pragma unroll
        for (int d = 0; d < 9; ++d) {
            const float* p = &w1s[(d*NP + jbase + j) * 8];
            float4 ab = *(const float4*)p;
            v2f Cv = *(const v2f*)(p + 4);
            v2f Av = (v2f){ab.x, ab.y}, Bv = (v2f){ab.z, ab.w};
            a += crr[d]*Av + ccc[d]*Bv + cbb[d]*Cv;
        }
        z2[j] = a;
    }

    int dc = 0;
    v2f b0v = (v2f){0.f,0.f}, b1v = (v2f){0.f,0.f}, b2v = (v2f){0.f,0.f};
    float pfin[ND];

    for (int it = 0; it < itMax; ++it) {
        const float* w1r = &w1s[(dc*NP + jbase) * 8];   // <=2 distinct addrs/wave
        const float* w2r = &w2s[jbase * 20];

        v2f acc2[ND];
        #pragma unroll
        for (int d = 0; d < ND; ++d) acc2[d] = (v2f){0.f, 0.f};

        #pragma unroll
        for (int j = 0; j < PPW; ++j) {
            const float* p = w1r + j*8;
            float4 ab = *(const float4*)p;
            v2f Cv = *(const v2f*)(p + 4);
            v2f Av = (v2f){ab.x, ab.y}, Bv = (v2f){ab.z, ab.w};
            v2f zv = z2[j];
            zv = b0v*Av + (b1v*Bv + (b2v*Cv + zv));
            z2[j] = zv;
            v2f hh;
            hh.x = fmaxf(zv.x, 0.f);
            hh.y = fmaxf(zv.y, 0.f);
            if (j < NREG) {
                #pragma unroll
                for (int d = 0; d < ND; ++d)
                    acc2[d] += hh * (v2f){w2reg[j][2*d], w2reg[j][2*d + 1]};
            } else {
                const float* qq = w2r + j*20;
                float4 w01 = *(const float4*)qq;
                float4 w23 = *(const float4*)(qq + 4);
                float4 w45 = *(const float4*)(qq + 8);
                float4 w67 = *(const float4*)(qq + 12);
                v2f w8 = *(const v2f*)(qq + 16);
                acc2[0] += hh * (v2f){w01.x, w01.y};
                acc2[1] += hh * (v2f){w01.z, w01.w};
                acc2[2] += hh * (v2f){w23.x, w23.y};
                acc2[3] += hh * (v2f){w23.z, w23.w};
                acc2[4] += hh * (v2f){w45.x, w45.y};
                acc2[5] += hh * (v2f){w45.z, w45.w};
                acc2[6] += hh * (v2f){w67.x, w67.y};
                acc2[7] += hh * (v2f){w67.z, w67.w};
                acc2[8] += hh * w8;
            }
        }

        const int buf = it & 1;
        #pragma unroll
        for (int d = 0; d < ND; ++d)
            parts[buf][wv][d][lw] = acc2[d].x + acc2[d].y;
        __syncthreads();

        float acc[ND];
        #pragma unroll
        for (int d = 0; d < ND; ++d) acc[d] = parts[buf][0][d][lw];
        #pragma unroll
        for (int ow = 1; ow < 4; ++ow) {
            #pragma unroll
            for (int d = 0; d < ND; ++d) acc[d] += parts[buf][ow][d][lw];
        }

        float m9 = fmaxf(fmaxf(fmaxf(acc[0],acc[1]), fmaxf(acc[2],acc[3])),
                         fmaxf(fmaxf(acc[4],acc[5]), fmaxf(acc[6],acc[7])));
        m9 = fmaxf(m9, acc[8]);
        float s = 0.f;
        #pragma unroll
        for (int d = 0; d < ND; ++d) { acc[d] = __expf(acc[d] - m9); s += acc[d]; }
        float inv = 1.f / s;
        float bv = -1.f; int bd = 0;
        #pragma unroll
        for (int d = 0; d < ND; ++d) {
            acc[d] *= inv;
            if (acc[d] > bv) { bv = acc[d]; bd = d; }
        }

        float bvv = active ? bv : -1.f;
        float vmax = bvv;
        #pragma unroll
        for (int off = 16; off >= 1; off >>= 1)
            vmax = fmaxf(vmax, __shfl_xor(vmax, off));
        if (joined) vmax = fmaxf(vmax, __shfl_xor(vmax, 32));
        const unsigned long long segMask =
            joined ? ~0ull : (h ? 0xFFFFFFFF00000000ull : 0x00000000FFFFFFFFull);
        unsigned long long msk = __ballot(active && (bvv == vmax)) & segMask;
        const bool valid = (msk != 0);
        int wl = valid ? (__ffsll(msk) - 1) : 0;   // lowest lane = lowest q
        int qw = __shfl(myq, wl);
        int dwn = __shfl(bd, wl);

        if (active && valid && myq == qw) {
            #pragma unroll
            for (int d = 0; d < ND; ++d) pfin[d] = acc[d];
            if (wv == 0) digit[idx][myq] = dwn;
            active = false;
        }
        const int pr = qw/9, pcc = qw%9, pb = (pr/3)*3 + pcc/3;
        b0v = (v2f)((valid && myr == pr)  ? 1.f : 0.f);
        b1v = (v2f)((valid && myc == pcc) ? 1.f : 0.f);
        b2v = (v2f)((valid && myb == pb)  ? 1.f : 0.f);
        if (valid) dc = dwn;
    }

    __syncthreads();
    if (wv == 0 && myq < 81) {
        #pragma unroll
        for (int d = 0; d < ND; ++d) pom[myq*ND + d] = pfin[d];
    }
    {
        const int slot = (tid < 128) ? 0 : 1;
        const int t = (tid < 128) ? tid : tid - 128;
        const bool doSlot = (slot == 0) || !joined;
        const int bd2 = slot ? s1 : s0;
        float* fob = out + (size_t)nBoards * (CELLS * ND) + (size_t)bd2 * (CELLS * ND);
        if (doSlot) {
            for (int i = t; i < CELLS * ND; i += 128) {
                int q = i / ND, d = i - q * ND;
                fob[i] = (digit[slot][q] == d) ? 1.f : 0.f;
            }
        }
    }
}

extern "C" void kernel_launch(void* const* d_in, const int* in_sizes, int n_in,
                              void* d_out, int out_size, void* d_ws, size_t ws_size,
                              hipStream_t stream) {
    const float* x  = (const float*)d_in[0];
    // d_in[1] is the constraint mask c — structurally known, not needed.
    const float* W1 = (const float*)d_in[2];
    const float* W2 = (const float*)d_in[3];
    float* out = (float*)d_out;
    float* ws  = (float*)d_ws;
    int nBoards = in_sizes[0] / (CELLS * ND);
    int* neArr  = (int*)ws + NE_OFF;
    int* ordArr = (int*)ws + ORD_OFF;
    prep_kernel<<<nBoards, 64, 0, stream>>>(x, W1, W2, ws, neArr, nBoards);
    scatter_kernel<<<66, 256, 0, stream>>>(neArr, ordArr, nBoards);
    sudoku_kernel<<<nBoards, 256, 0, stream>>>(x, ws, ordArr, out, nBoards);
}

// Round 22
// 119.200 us; speedup vs baseline: 1.0304x; 1.0304x over previous
//
#include <hip/hip_runtime.h>

#define CELLS 81
#define ND 9
#define HID 100
#define NP 52    // padded unit-pairs: 50 real + 2 zero
#define PPW 13   // pairs per wave (4 waves x 13 = 52)
#define NREG 8   // W2 pairs persisted in VGPRs per wave (rest via LDS)

typedef float v2f __attribute__((ext_vector_type(2)));

#define W1P_SZ (9 * NP * 8)           // 3744 floats
#define W2P_OFF W1P_SZ                // 3744
#define W2P_SZ (NP * 20)              // 1040 floats
#define NE_OFF (W2P_OFF + W2P_SZ)     // 4784: ne_arr[1024] (int)
#define ORD_OFF (NE_OFF + 1024)       // 5808: order[2*1024] (int)

// Prolog 1: pack weight tables (first ~75 blocks' worth of gids) and write
// each board's empty-count to ne_arr[b]. NO atomics, NO memset dependency.
__global__ __launch_bounds__(64) void prep_kernel(
    const float* __restrict__ x_all,
    const float* __restrict__ W1, const float* __restrict__ W2,
    float* __restrict__ ws, int* __restrict__ ne_arr, int nBoards)
{
    const int b = blockIdx.x, t = threadIdx.x;
    const int gid = b * 64 + t;

    if (gid < W1P_SZ) {
        int i = gid >> 3, k = gid & 7;
        int d = i / NP, j = i - d * NP;
        float v = 0.f;
        if (j < 50 && k < 6) {
            int u = 2 * j + (k & 1);
            v = W1[u*27 + (k >> 1) * 9 + d];
        }
        ws[gid] = v;
    } else if (gid < NE_OFF) {
        int f = gid - W2P_OFF;
        int j = f / 20, k = f - j * 20;
        float v = 0.f;
        if (j < 50 && k < 18) {
            int d = k >> 1, u = 2 * j + (k & 1);
            v = W2[d*HID + u];
        }
        ws[gid] = v;
    }

    if (b >= nBoards) return;

    const float* xb = x_all + (size_t)b * (CELLS * ND);
    float mx = 0.f;
    #pragma unroll
    for (int d = 0; d < ND; ++d) mx = fmaxf(mx, xb[t*ND + d]);
    bool e1 = (mx < 0.5f);
    bool e2 = false;
    if (t < CELLS - 64) {
        float m2 = 0.f;
        #pragma unroll
        for (int d = 0; d < ND; ++d) m2 = fmaxf(m2, xb[(64+t)*ND + d]);
        e2 = (m2 < 0.5f);
    }
    unsigned long long m1 = __ballot(e1), m2b = __ballot(e2);
    if (t == 0) {
        int ne = __popcll(m1) + __popcll(m2b);
        if (ne > 64) ne = 64;
        ne_arr[b] = ne;
    }
}

// Prolog 2: deterministic atomic-free counting sort. 66 blocks: blocks 0..64
// each own one ne-bucket (emit members in board-id order via wave-0 ballot
// compaction); block 65 writes the -1 tail and odd-parity hole so EVERY
// order[] slot is written each replay (no memset needed). Layout identical
// to R13: bigs (ne>32) joined, descending ne; smalls paired adjacent.
// (R21 lesson: snake/boustrophedon slot permutation REGRESSED -3.4us; the
// b->CU stride model was wrong. Natural sorted order stays.)
__global__ __launch_bounds__(256) void scatter_kernel(
    const int* __restrict__ ne_arr, int* __restrict__ order, int nBoards)
{
    __shared__ int sh_ne[1024];
    __shared__ int cntS[65];
    __shared__ int baseS, nBigS, nUsedS, oddS;
    const int t = threadIdx.x;
    const int bk = blockIdx.x;

    for (int i = t; i < 1024; i += 256)
        sh_ne[i] = (i < nBoards) ? ne_arr[i] : -1;
    __syncthreads();
    if (t < 65) {
        int c = 0;
        for (int j = 0; j < 1024; ++j) c += (sh_ne[j] == t) ? 1 : 0;
        cntS[t] = c;
    }
    __syncthreads();

    if (bk < 65) {
        if (t == 0) {
            int acc = 0, nb = 0;
            for (int k = 64; k > bk; --k) acc += cntS[k];
            for (int k = 64; k > 32; --k) nb += cntS[k];
            baseS = acc; nBigS = nb;
        }
        __syncthreads();
        const int base = baseS, nBig = nBigS;
        if (t < 64) {                       // wave 0: ballot-compact members
            int r = 0;
            for (int chunk = 0; chunk < 16; ++chunk) {
                int i = chunk * 64 + t;
                bool m = (sh_ne[i] == bk);
                unsigned long long mk = __ballot(m);
                if (m) {
                    int rk = r + __popcll(mk & ((1ull << t) - 1ull));
                    int pos = base + rk;
                    if (bk > 32) {          // joined big: own block
                        order[2*pos] = i; order[2*pos + 1] = i;
                    } else {
                        int rr = pos - nBig;
                        int blk = nBig + (rr >> 1);
                        order[2*blk + (rr & 1)] = i;
                    }
                }
                r += __popcll(mk);
            }
        }
    } else {
        if (t == 0) {
            int nb = 0, ns = 0;
            for (int k = 64; k > 32; --k) nb += cntS[k];
            for (int k = 0; k <= 32; ++k) ns += cntS[k];
            nBigS = nb;
            nUsedS = nb + (ns + 1) / 2;
            oddS = ns & 1;
        }
        __syncthreads();
        const int nUsed = nUsedS;
        for (int i = nUsed + t; i < 1024; i += 256) {
            order[2*i] = -1; order[2*i + 1] = -1;
        }
        if (t == 0 && oddS && nUsed > 0)
            order[2*(nUsed - 1) + 1] = -1;  // lone small -> joined mode
    }
}

// R13-proven solver (byte-identical): 40.4 KB LDS -> 4 blocks/CU. W2 for
// NREG pairs in registers, loaded from LDS (R15 lesson: global-loaded
// uniforms get rematerialized as in-loop global loads at ~200cy each).
__global__ __launch_bounds__(256, 2) void sudoku_kernel(
    const float* __restrict__ x_all,
    const float* __restrict__ ws,
    const int* __restrict__ order,
    float* __restrict__ out, int nBoards)
{
    const int tid = threadIdx.x;      // 4 waves x 13 pairs
    const int wv  = tid >> 6;
    const int lw  = tid & 63;
    const int h   = lw >> 5;          // 32-lane segment within wave
    const int jbase = wv * PPW;

    const int s0  = order[2 * blockIdx.x];
    const int s1r = order[2 * blockIdx.x + 1];
    if (s0 < 0) return;
    const int s1 = (s1r < 0) ? s0 : s1r;
    const bool joined = (s0 == s1);   // one 64-lane board (big or lone small)
    const int myBoard = h ? s1 : s0;
    const int idx = joined ? 0 : h;   // cnt/digit slot

    float* pom = out + (size_t)myBoard * (CELLS * ND);

    __shared__ __align__(16) float w1s[W1P_SZ];      // 14976 B
    __shared__ __align__(16) float w2s[W2P_SZ];      // 4160 B
    __shared__ float parts[2][4][ND][64];            // 18432 B, conflict-free
    __shared__ float cnt[2][3 * 81];                 // 1944 B
    __shared__ int   digit[2][CELLS];                // 648 B

    for (int i = tid; i < W1P_SZ / 4; i += 256)
        ((float4*)w1s)[i] = ((const float4*)ws)[i];
    for (int i = tid; i < W2P_SZ / 4; i += 256)
        ((float4*)w2s)[i] = ((const float4*)(ws + W2P_OFF))[i];
    for (int i = tid; i < 2 * 243; i += 256) (&cnt[0][0])[i] = 0.f;
    __syncthreads();

    float w2reg[NREG][18];
    #pragma unroll
    for (int j = 0; j < NREG; ++j) {
        const float* qq = &w2s[(jbase + j) * 20];
        #pragma unroll
        for (int k = 0; k < 18; ++k) w2reg[j][k] = qq[k];
    }

    {
        const int slot = (tid < 128) ? 0 : 1;
        const int t = (tid < 128) ? tid : tid - 128;
        const bool doSlot = (slot == 0) || !joined;
        const int bd = slot ? s1 : s0;
        const float* xb = x_all + (size_t)bd * (CELLS * ND);
        float* pob = out + (size_t)bd * (CELLS * ND);
        if (doSlot) {
            if (t < CELLS) {
                int dig = -1;
                #pragma unroll
                for (int d = 0; d < ND; ++d)
                    if (dig < 0 && xb[t*ND + d] > 0.5f) dig = d;
                digit[slot][t] = dig;
                if (dig >= 0) {
                    int r = t/9, c = t%9, b = (r/3)*3 + c/3;
                    atomicAdd(&cnt[slot][r*9 + dig], 1.f);
                    atomicAdd(&cnt[slot][81 + c*9 + dig], 1.f);
                    atomicAdd(&cnt[slot][162 + b*9 + dig], 1.f);
                }
            }
            for (int i = t; i < CELLS * ND; i += 128) pob[i] = xb[i];
        }
    }
    __syncthreads();

    const int rank = joined ? lw : (lw & 31);
    int myq = 127;
    int ne0 = 0, ne1 = 0;
    for (int q = 0; q < CELLS; ++q)
        if (digit[0][q] < 0) { if (idx == 0 && ne0 == rank) myq = q; ++ne0; }
    if (!joined) {
        for (int q = 0; q < CELLS; ++q)
            if (digit[1][q] < 0) { if (idx == 1 && ne1 == rank) myq = q; ++ne1; }
    } else ne1 = ne0;
    if (ne0 > 64) ne0 = 64;
    if (ne1 > 64) ne1 = 64;
    const int ne_mine = idx ? ne1 : ne0;
    const int itMax = max(ne0, ne1);
    bool active = (rank < ne_mine);

    const int myr = (myq < 81) ? myq / 9 : 0;
    const int myc = (myq < 81) ? myq % 9 : 0;
    const int myb = (myr / 3) * 3 + myc / 3;

    float crr[9], ccc[9], cbb[9];
    #pragma unroll
    for (int j = 0; j < 9; ++j) {
        crr[j] = cnt[idx][myr*9 + j];
        ccc[j] = cnt[idx][81 + myc*9 + j];
        cbb[j] = cnt[idx][162 + myb*9 + j];
    }
    v2f z2[PPW];
    #pragma unroll
    for (int j = 0; j < PPW; ++j) {
        v2f a = (v2f){0.f, 0.f};
        #pragma unroll
        for (int d = 0; d < 9; ++d) {
            const float* p = &w1s[(d*NP + jbase + j) * 8];
            float4 ab = *(const float4*)p;
            v2f Cv = *(const v2f*)(p + 4);
            v2f Av = (v2f){ab.x, ab.y}, Bv = (v2f){ab.z, ab.w};
            a += crr[d]*Av + ccc[d]*Bv + cbb[d]*Cv;
        }
        z2[j] = a;
    }

    int dc = 0;
    v2f b0v = (v2f){0.f,0.f}, b1v = (v2f){0.f,0.f}, b2v = (v2f){0.f,0.f};
    float pfin[ND];

    for (int it = 0; it < itMax; ++it) {
        const float* w1r = &w1s[(dc*NP + jbase) * 8];   // <=2 distinct addrs/wave
        const float* w2r = &w2s[jbase * 20];

        v2f acc2[ND];
        #pragma unroll
        for (int d = 0; d < ND; ++d) acc2[d] = (v2f){0.f, 0.f};

        #pragma unroll
        for (int j = 0; j < PPW; ++j) {
            const float* p = w1r + j*8;
            float4 ab = *(const float4*)p;
            v2f Cv = *(const v2f*)(p + 4);
            v2f Av = (v2f){ab.x, ab.y}, Bv = (v2f){ab.z, ab.w};
            v2f zv = z2[j];
            zv = b0v*Av + (b1v*Bv + (b2v*Cv + zv));
            z2[j] = zv;
            v2f hh;
            hh.x = fmaxf(zv.x, 0.f);
            hh.y = fmaxf(zv.y, 0.f);
            if (j < NREG) {
                #pragma unroll
                for (int d = 0; d < ND; ++d)
                    acc2[d] += hh * (v2f){w2reg[j][2*d], w2reg[j][2*d + 1]};
            } else {
                const float* qq = w2r + j*20;
                float4 w01 = *(const float4*)qq;
                float4 w23 = *(const float4*)(qq + 4);
                float4 w45 = *(const float4*)(qq + 8);
                float4 w67 = *(const float4*)(qq + 12);
                v2f w8 = *(const v2f*)(qq + 16);
                acc2[0] += hh * (v2f){w01.x, w01.y};
                acc2[1] += hh * (v2f){w01.z, w01.w};
                acc2[2] += hh * (v2f){w23.x, w23.y};
                acc2[3] += hh * (v2f){w23.z, w23.w};
                acc2[4] += hh * (v2f){w45.x, w45.y};
                acc2[5] += hh * (v2f){w45.z, w45.w};
                acc2[6] += hh * (v2f){w67.x, w67.y};
                acc2[7] += hh * (v2f){w67.z, w67.w};
                acc2[8] += hh * w8;
            }
        }

        const int buf = it & 1;
        #pragma unroll
        for (int d = 0; d < ND; ++d)
            parts[buf][wv][d][lw] = acc2[d].x + acc2[d].y;
        __syncthreads();

        float acc[ND];
        #pragma unroll
        for (int d = 0; d < ND; ++d) acc[d] = parts[buf][0][d][lw];
        #pragma unroll
        for (int ow = 1; ow < 4; ++ow) {
            #pragma unroll
            for (int d = 0; d < ND; ++d) acc[d] += parts[buf][ow][d][lw];
        }

        float m9 = fmaxf(fmaxf(fmaxf(acc[0],acc[1]), fmaxf(acc[2],acc[3])),
                         fmaxf(fmaxf(acc[4],acc[5]), fmaxf(acc[6],acc[7])));
        m9 = fmaxf(m9, acc[8]);
        float s = 0.f;
        #pragma unroll
        for (int d = 0; d < ND; ++d) { acc[d] = __expf(acc[d] - m9); s += acc[d]; }
        float inv = 1.f / s;
        float bv = -1.f; int bd = 0;
        #pragma unroll
        for (int d = 0; d < ND; ++d) {
            acc[d] *= inv;
            if (acc[d] > bv) { bv = acc[d]; bd = d; }
        }

        float bvv = active ? bv : -1.f;
        float vmax = bvv;
        #pragma unroll
        for (int off = 16; off >= 1; off >>= 1)
            vmax = fmaxf(vmax, __shfl_xor(vmax, off));
        if (joined) vmax = fmaxf(vmax, __shfl_xor(vmax, 32));
        const unsigned long long segMask =
            joined ? ~0ull : (h ? 0xFFFFFFFF00000000ull : 0x00000000FFFFFFFFull);
        unsigned long long msk = __ballot(active && (bvv == vmax)) & segMask;
        const bool valid = (msk != 0);
        int wl = valid ? (__ffsll(msk) - 1) : 0;   // lowest lane = lowest q
        int qw = __shfl(myq, wl);
        int dwn = __shfl(bd, wl);

        if (active && valid && myq == qw) {
            #pragma unroll
            for (int d = 0; d < ND; ++d) pfin[d] = acc[d];
            if (wv == 0) digit[idx][myq] = dwn;
            active = false;
        }
        const int pr = qw/9, pcc = qw%9, pb = (pr/3)*3 + pcc/3;
        b0v = (v2f)((valid && myr == pr)  ? 1.f : 0.f);
        b1v = (v2f)((valid && myc == pcc) ? 1.f : 0.f);
        b2v = (v2f)((valid && myb == pb)  ? 1.f : 0.f);
        if (valid) dc = dwn;
    }

    __syncthreads();
    if (wv == 0 && myq < 81) {
        #pragma unroll
        for (int d = 0; d < ND; ++d) pom[myq*ND + d] = pfin[d];
    }
    {
        const int slot = (tid < 128) ? 0 : 1;
        const int t = (tid < 128) ? tid : tid - 128;
        const bool doSlot = (slot == 0) || !joined;
        const int bd2 = slot ? s1 : s0;
        float* fob = out + (size_t)nBoards * (CELLS * ND) + (size_t)bd2 * (CELLS * ND);
        if (doSlot) {
            for (int i = t; i < CELLS * ND; i += 128) {
                int q = i / ND, d = i - q * ND;
                fob[i] = (digit[slot][q] == d) ? 1.f : 0.f;
            }
        }
    }
}

extern "C" void kernel_launch(void* const* d_in, const int* in_sizes, int n_in,
                              void* d_out, int out_size, void* d_ws, size_t ws_size,
                              hipStream_t stream) {
    const float* x  = (const float*)d_in[0];
    // d_in[1] is the constraint mask c — structurally known, not needed.
    const float* W1 = (const float*)d_in[2];
    const float* W2 = (const float*)d_in[3];
    float* out = (float*)d_out;
    float* ws  = (float*)d_ws;
    int nBoards = in_sizes[0] / (CELLS * ND);
    int* neArr  = (int*)ws + NE_OFF;
    int* ordArr = (int*)ws + ORD_OFF;
    prep_kernel<<<nBoards, 64, 0, stream>>>(x, W1, W2, ws, neArr, nBoards);
    scatter_kernel<<<66, 256, 0, stream>>>(neArr, ordArr, nBoards);
    sudoku_kernel<<<nBoards, 256, 0, stream>>>(x, ws, ordArr, out, nBoards);
}